// Round 4
// baseline (182.278 us; speedup 1.0000x reference)
//
#include <hip/hip_runtime.h>
#include <hip/hip_bf16.h>
#include <cstddef>

// ---------------------------------------------------------------------------
// LinearAttention — round 4: pre-normalized transposed xn buffer.
//
// k_norm writes xn[tok][c] = bf16(x * rsqrt(sum_c x^2)) once; k1/k5 then load
// each MFMA x-fragment as a single dwordx4 (8 vector loads/lane vs 64 scalar),
// removing the duplicated norm work and the latency-serialized scalar staging
// that kept MfmaUtil/VALUBusy/HBM all <6% in rounds 2-3.
// MFMA structure, fragment pairing, and reduction pipeline are verbatim from
// the passing round-3 kernel (absmax 0.03).
// ---------------------------------------------------------------------------

typedef __attribute__((ext_vector_type(8))) short short8;
typedef __attribute__((ext_vector_type(4))) float f32x4;

static constexpr int   NTOK = 65536;                        // H*W
static constexpr float NORM_SCALE_F = 11.313708498984761f;  // sqrt(128)
static constexpr float SCALE_F      = 0.17677669529663687f; // 1/sqrt(32)

__device__ __forceinline__ unsigned short f2bf(float f) {
  __hip_bfloat16 h = __float2bfloat16(f);
  return *reinterpret_cast<unsigned short*>(&h);
}
__device__ __forceinline__ short sbf(float f) { return (short)f2bf(f); }

// ---------------------------------------------------------------- k0:
// pack q/k/v weights (folded with (gamma1+1)*sqrt(128)) frag-linear bf16:
// Wp[((rt*4+ks)*64 + ln)*8 + j] = w_qkv[rt*16+(ln&15)][ks*32+(ln>>4)*8+j]*g1s
__global__ __launch_bounds__(256) void k0_pack(const float* __restrict__ w_qkv,
                                               const float* __restrict__ gamma1,
                                               unsigned short* __restrict__ Wp) {
  const int id = blockIdx.x * 256 + threadIdx.x;   // < 49152
  const int m = id / 16384, p = id % 16384;
  const int j = p & 7, ln = (p >> 3) & 63, frag = p >> 9;
  const int ks = frag & 3, rt = frag >> 2;
  const int row = rt * 16 + (ln & 15);
  const int c = ks * 32 + (ln >> 4) * 8 + j;
  const float v = w_qkv[(m * 128 + row) * 128 + c] * (gamma1[c] + 1.0f) * NORM_SCALE_F;
  Wp[id] = f2bf(v);
}

// ---------------------------------------------------------------- k_norm:
// xn[tok][c] = bf16(x[c][tok] * rsqrt(sum_c x^2)). 4 threads per token
// (32 channels each, 2 shfl_xor to combine). 1024 blocks x 256 threads.
__global__ __launch_bounds__(256) void k_norm(const float* __restrict__ x,
                                              unsigned short* __restrict__ xn) {
  const int t = threadIdx.x;
  const int tok = blockIdx.x * 64 + (t >> 2);
  const int cg = (t & 3) * 32;
  float v[32];
  float sq = 0.f;
  #pragma unroll
  for (int j = 0; j < 32; ++j) {
    v[j] = x[(size_t)(cg + j) * NTOK + tok];
    sq += v[j] * v[j];
  }
  sq += __shfl_xor(sq, 1, 64);
  sq += __shfl_xor(sq, 2, 64);
  const float s = rsqrtf(sq);
  #pragma unroll
  for (int g = 0; g < 4; ++g) {
    short8 o;
    #pragma unroll
    for (int j = 0; j < 8; ++j) o[j] = sbf(v[g * 8 + j] * s);
    *reinterpret_cast<short8*>(xn + (size_t)tok * 128 + cg + g * 8) = o;
  }
}

// ---------------------------------------------------------------- k1:
// 256 blocks x 512 threads (8 waves); wave owns 32 tokens. Swapped GEMMs,
// in-register context, LDS-atomic block reduction -> CpAll[block][4224].
__global__ __launch_bounds__(512) void k1_kv(const unsigned short* __restrict__ xn,
                                             const unsigned short* __restrict__ Wkp,
                                             const unsigned short* __restrict__ Wvp,
                                             float* __restrict__ CpAll) {
  __shared__ float cred[4224];     // [0,4096): C[h][d][e]; [4096,4224): S[h][d]
  const int tid = threadIdx.x, wv = tid >> 6, ln = tid & 63;
  const int g4 = ln >> 4, t16 = ln & 15;
  const int n0 = (blockIdx.x * 8 + wv) * 32;

  for (int i = tid; i < 4224; i += 512) cred[i] = 0.f;
  __syncthreads();

  // ---- x^T A-frags straight from xn (lane: token = tg*16+t16, c = ks*32+g4*8+j)
  short8 xf[2][4];
  #pragma unroll
  for (int tg = 0; tg < 2; ++tg)
    #pragma unroll
    for (int ks = 0; ks < 4; ++ks)
      xf[tg][ks] = *reinterpret_cast<const short8*>(
          xn + (size_t)(n0 + tg * 16 + t16) * 128 + ks * 32 + g4 * 8);

  #pragma unroll
  for (int h = 0; h < 4; ++h) {
    // ---- k^T GEMM: D[token][d]  (A = x^T, B = Wk)
    f32x4 ka[2][2] = {};   // [mt][tg]
    #pragma unroll
    for (int ks = 0; ks < 4; ++ks) {
      const short8 b0 = *reinterpret_cast<const short8*>(Wkp + (((2 * h + 0) * 4 + ks) * 64 + ln) * 8);
      const short8 b1 = *reinterpret_cast<const short8*>(Wkp + (((2 * h + 1) * 4 + ks) * 64 + ln) * 8);
      #pragma unroll
      for (int tg = 0; tg < 2; ++tg) {
        ka[0][tg] = __builtin_amdgcn_mfma_f32_16x16x32_bf16(xf[tg][ks], b0, ka[0][tg], 0, 0, 0);
        ka[1][tg] = __builtin_amdgcn_mfma_f32_16x16x32_bf16(xf[tg][ks], b1, ka[1][tg], 0, 0, 0);
      }
    }
    // ---- exp -> paired A-frag (j = tg*4+r), S partial -> LDS atomic
    short8 keA[2];
    #pragma unroll
    for (int mt = 0; mt < 2; ++mt) {
      float sl = 0.f;
      short8 u;
      #pragma unroll
      for (int tg = 0; tg < 2; ++tg)
        #pragma unroll
        for (int r = 0; r < 4; ++r) {
          const float e = __expf(ka[mt][tg][r]);
          sl += e;
          u[tg * 4 + r] = sbf(e);
        }
      keA[mt] = u;
      sl += __shfl_xor(sl, 16, 64);
      sl += __shfl_xor(sl, 32, 64);
      if (g4 == 0) atomicAdd(&cred[4096 + h * 32 + mt * 16 + t16], sl);
    }
    // ---- v^T GEMM
    f32x4 va[2][2] = {};
    #pragma unroll
    for (int ks = 0; ks < 4; ++ks) {
      const short8 b0 = *reinterpret_cast<const short8*>(Wvp + (((2 * h + 0) * 4 + ks) * 64 + ln) * 8);
      const short8 b1 = *reinterpret_cast<const short8*>(Wvp + (((2 * h + 1) * 4 + ks) * 64 + ln) * 8);
      #pragma unroll
      for (int tg = 0; tg < 2; ++tg) {
        va[0][tg] = __builtin_amdgcn_mfma_f32_16x16x32_bf16(xf[tg][ks], b0, va[0][tg], 0, 0, 0);
        va[1][tg] = __builtin_amdgcn_mfma_f32_16x16x32_bf16(xf[tg][ks], b1, va[1][tg], 0, 0, 0);
      }
    }
    short8 vB[2];
    #pragma unroll
    for (int et = 0; et < 2; ++et) {
      short8 u;
      #pragma unroll
      for (int tg = 0; tg < 2; ++tg)
        #pragma unroll
        for (int r = 0; r < 4; ++r)
          u[tg * 4 + r] = sbf(va[et][tg][r]);
      vB[et] = u;
    }
    // ---- context MFMA (K=32 over paired tokens) + atomic drain
    #pragma unroll
    for (int dt = 0; dt < 2; ++dt)
      #pragma unroll
      for (int et = 0; et < 2; ++et) {
        f32x4 zc = {0.f, 0.f, 0.f, 0.f};
        zc = __builtin_amdgcn_mfma_f32_16x16x32_bf16(keA[dt], vB[et], zc, 0, 0, 0);
        #pragma unroll
        for (int r = 0; r < 4; ++r)
          atomicAdd(&cred[h * 1024 + (dt * 16 + g4 * 4 + r) * 32 + et * 16 + t16], zc[r]);
      }
  }

  __syncthreads();
  for (int i = tid; i < 4224; i += 512)
    CpAll[(size_t)blockIdx.x * 4224 + i] = cred[i];
}

// ---------------------------------------------------------------- k3a:
// reduce 256 block-partials (4224 each) in 8 chunks of 32.
__global__ __launch_bounds__(256) void k3a_reduce(const float* __restrict__ CpAll,
                                                  float* __restrict__ Cpp) {
  __shared__ float red[256];
  const int t = threadIdx.x;
  const int eg = blockIdx.x;   // 0..32
  const int ch = blockIdx.y;   // 0..7
  const int e = eg * 128 + (t & 127);   // < 4224 exactly (33*128)
  const int half = t >> 7;
  float s = 0.f;
  for (int bb = 0; bb < 16; ++bb) {
    const int b = ch * 32 + half * 16 + bb;
    s += CpAll[(size_t)b * 4224 + e];
  }
  red[t] = s;
  __syncthreads();
  if (t < 128) Cpp[ch * 4224 + eg * 128 + t] = red[t] + red[t + 128];
}

// ---------------------------------------------------------------- k3b1:
// final reduce + memory-kv terms + divide -> ctx[4096] (proven)
__global__ __launch_bounds__(256) void k3b1_ctx(const float* __restrict__ Cpp,
                                                const float* __restrict__ mem_kv,
                                                float* __restrict__ ctx) {
  __shared__ float allv[4224];
  const int t = threadIdx.x;
  for (int e = t; e < 4224; e += 256) {
    float s = 0.f;
    #pragma unroll
    for (int c = 0; c < 8; ++c) s += Cpp[c * 4224 + e];
    allv[e] = s;
  }
  __syncthreads();
  for (int e = t; e < 4224; e += 256) {
    if (e < 4096) {
      const int hh = e >> 10, d = (e >> 5) & 31, ev = e & 31;
      float add = 0.f;
      #pragma unroll
      for (int m = 0; m < 4; ++m)
        add += __expf(mem_kv[(hh * 32 + d) * 4 + m]) * mem_kv[512 + (hh * 32 + ev) * 4 + m];
      allv[e] += add;
    } else {
      const int si = e - 4096;
      const int hh = si >> 5, d = si & 31;
      float add = 0.f;
      #pragma unroll
      for (int m = 0; m < 4; ++m) add += __expf(mem_kv[(hh * 32 + d) * 4 + m]);
      allv[e] += add;
    }
  }
  __syncthreads();
  for (int e = t; e < 4096; e += 256)
    ctx[e] = allv[e] / allv[4096 + (e >> 5)];
}

// ---------------------------------------------------------------- k3b2:
// W2p A-frags: frag (ot,h), elem j: W2[ot*16+(ln&15)][h*32+(j>>2)*16+(ln>>4)*4+(j&3)]
// where W2[o][h*32+d] = SCALE * sum_e w_out[o][h*32+e] * ctx[h][d][e].
__global__ __launch_bounds__(256) void k3b2_w2(const float* __restrict__ ctx,
                                               const float* __restrict__ w_out,
                                               unsigned short* __restrict__ W2p) {
  const int base = (blockIdx.x * 256 + threadIdx.x) * 8;  // 2048 threads * 8 = 16384
  const int ln = (base >> 3) & 63;
  const int frag = base >> 9;          // 0..31
  const int h = frag & 3, ot = frag >> 2;
  const int o = ot * 16 + (ln & 15);
  float wrow[32];
  #pragma unroll
  for (int e = 0; e < 32; ++e) wrow[e] = w_out[o * 128 + h * 32 + e];
  short8 out8;
  #pragma unroll
  for (int j = 0; j < 8; ++j) {
    const int d = (j >> 2) * 16 + ((ln >> 4) << 2) + (j & 3);
    float s = 0.f;
    #pragma unroll
    for (int e = 0; e < 32; ++e)
      s += wrow[e] * ctx[h * 1024 + d * 32 + e];
    out8[j] = sbf(s * SCALE_F);
  }
  *reinterpret_cast<short8*>(W2p + base) = out8;
}

// ---------------------------------------------------------------- k5:
// 512 blocks x 256 threads (4 waves); wave owns 32 tokens. NO LDS.
// q GEMM (orig orientation) -> softmax over d -> paired B-frags -> W2 GEMM
// -> +bias -> rmsnorm -> store y.
__global__ __launch_bounds__(256) void k5_out(const unsigned short* __restrict__ xn,
                                              const unsigned short* __restrict__ Wqp,
                                              const unsigned short* __restrict__ W2p,
                                              const float* __restrict__ b_out,
                                              const float* __restrict__ gamma2,
                                              float* __restrict__ y) {
  const int tid = threadIdx.x, wv = tid >> 6, ln = tid & 63;
  const int g4 = ln >> 4, t16 = ln & 15;
  const int n0 = (blockIdx.x * 4 + wv) * 32;

  // ---- x B-frags straight from xn (lane: c = ks*32+g4*8+j, token = tg*16+t16)
  short8 xf[2][4];
  #pragma unroll
  for (int tg = 0; tg < 2; ++tg)
    #pragma unroll
    for (int ks = 0; ks < 4; ++ks)
      xf[tg][ks] = *reinterpret_cast<const short8*>(
          xn + (size_t)(n0 + tg * 16 + t16) * 128 + ks * 32 + g4 * 8);

  // ---- q GEMM per head + softmax over d -> paired B-frags qB[h][tg]
  short8 qB[4][2];
  #pragma unroll
  for (int h = 0; h < 4; ++h) {
    f32x4 qa[2][2] = {};   // [rtl][tg]; lane: hd = h*32+rtl*16+g4*4+r, tok = t16
    #pragma unroll
    for (int ks = 0; ks < 4; ++ks) {
      const short8 a0 = *reinterpret_cast<const short8*>(Wqp + (((2 * h + 0) * 4 + ks) * 64 + ln) * 8);
      const short8 a1 = *reinterpret_cast<const short8*>(Wqp + (((2 * h + 1) * 4 + ks) * 64 + ln) * 8);
      #pragma unroll
      for (int tg = 0; tg < 2; ++tg) {
        qa[0][tg] = __builtin_amdgcn_mfma_f32_16x16x32_bf16(a0, xf[tg][ks], qa[0][tg], 0, 0, 0);
        qa[1][tg] = __builtin_amdgcn_mfma_f32_16x16x32_bf16(a1, xf[tg][ks], qa[1][tg], 0, 0, 0);
      }
    }
    #pragma unroll
    for (int tg = 0; tg < 2; ++tg) {
      float ev[2][4];
      float ss = 0.f;
      #pragma unroll
      for (int rtl = 0; rtl < 2; ++rtl)
        #pragma unroll
        for (int r = 0; r < 4; ++r) {
          ev[rtl][r] = __expf(qa[rtl][tg][r]);
          ss += ev[rtl][r];
        }
      ss += __shfl_xor(ss, 16, 64);
      ss += __shfl_xor(ss, 32, 64);
      const float inv = 1.0f / ss;
      short8 u;
      #pragma unroll
      for (int rtl = 0; rtl < 2; ++rtl)
        #pragma unroll
        for (int r = 0; r < 4; ++r)
          u[rtl * 4 + r] = sbf(ev[rtl][r] * inv);
      qB[h][tg] = u;   // B-frag slot j: hd = h*32+(j>>2)*16+g4*4+(j&3)
    }
  }

  // ---- W2 GEMM: z[o][tok]
  f32x4 z[8][2] = {};
  #pragma unroll
  for (int h = 0; h < 4; ++h)
    #pragma unroll
    for (int ot = 0; ot < 8; ++ot) {
      const short8 a = *reinterpret_cast<const short8*>(W2p + ((ot * 4 + h) * 64 + ln) * 8);
      #pragma unroll
      for (int tg = 0; tg < 2; ++tg)
        z[ot][tg] = __builtin_amdgcn_mfma_f32_16x16x32_bf16(a, qB[h][tg], z[ot][tg], 0, 0, 0);
    }

  // ---- + bias, rmsnorm over channels, store
  float ssq[2] = {0.f, 0.f};
  #pragma unroll
  for (int ot = 0; ot < 8; ++ot) {
    const float4 bb = *reinterpret_cast<const float4*>(b_out + ot * 16 + g4 * 4);
    const float barr[4] = {bb.x, bb.y, bb.z, bb.w};
    #pragma unroll
    for (int tg = 0; tg < 2; ++tg)
      #pragma unroll
      for (int r = 0; r < 4; ++r) {
        const float zb = z[ot][tg][r] + barr[r];
        z[ot][tg][r] = zb;
        ssq[tg] += zb * zb;
      }
  }
  float rr[2];
  #pragma unroll
  for (int tg = 0; tg < 2; ++tg) {
    float s = ssq[tg];
    s += __shfl_xor(s, 16, 64);
    s += __shfl_xor(s, 32, 64);
    rr[tg] = rsqrtf(s);
  }
  #pragma unroll
  for (int ot = 0; ot < 8; ++ot) {
    const float4 gg = *reinterpret_cast<const float4*>(gamma2 + ot * 16 + g4 * 4);
    const float garr[4] = {gg.x, gg.y, gg.z, gg.w};
    #pragma unroll
    for (int tg = 0; tg < 2; ++tg)
      #pragma unroll
      for (int r = 0; r < 4; ++r) {
        const int row = ot * 16 + g4 * 4 + r;
        y[(size_t)row * NTOK + n0 + tg * 16 + t16] =
            z[ot][tg][r] * rr[tg] * (garr[r] + 1.0f) * NORM_SCALE_F;
      }
  }
}

// ---------------------------------------------------------------------------
extern "C" void kernel_launch(void* const* d_in, const int* in_sizes, int n_in,
                              void* d_out, int out_size, void* d_ws, size_t ws_size,
                              hipStream_t stream) {
  const float* x      = (const float*)d_in[0];
  const float* gamma1 = (const float*)d_in[1];
  const float* w_qkv  = (const float*)d_in[2];
  const float* mem_kv = (const float*)d_in[3];
  const float* w_out  = (const float*)d_in[4];
  const float* b_out  = (const float*)d_in[5];
  const float* gamma2 = (const float*)d_in[6];
  float* out = (float*)d_out;
  float* ws  = (float*)d_ws;

  // ws layout (float slots):
  //   [0, 32768)            packed bf16 weights Wqp/Wkp/Wvp/W2p (65536 ushorts)
  //   [32768, 1114112)      CpAll 256*4224
  //   [1114112, 1147904)    Cpp 8*4224
  //   [1147904, 1152000)    ctx 4096
  //   [1152000, 5346304)    xn 65536*128 bf16 (8388608 ushorts)
  // total ~21.4 MB
  unsigned short* Wqp = (unsigned short*)ws;     // 16384 ushorts
  unsigned short* Wkp = Wqp + 16384;
  unsigned short* Wvp = Wkp + 16384;
  unsigned short* W2p = Wvp + 16384;
  float* CpAll = ws + 32768;            // 256*4224
  float* Cpp   = CpAll + 1081344;       // 8*4224
  float* ctx   = Cpp + 33792;           // 4096
  unsigned short* xn = (unsigned short*)(ws + 1152000);  // 65536*128 bf16

  hipLaunchKernelGGL(k0_pack,    dim3(192),    dim3(256), 0, stream, w_qkv, gamma1, Wqp);
  hipLaunchKernelGGL(k_norm,     dim3(1024),   dim3(256), 0, stream, x, xn);
  hipLaunchKernelGGL(k1_kv,      dim3(256),    dim3(512), 0, stream, xn, Wkp, Wvp, CpAll);
  hipLaunchKernelGGL(k3a_reduce, dim3(33, 8),  dim3(256), 0, stream, CpAll, Cpp);
  hipLaunchKernelGGL(k3b1_ctx,   dim3(1),      dim3(256), 0, stream, Cpp, mem_kv, ctx);
  hipLaunchKernelGGL(k3b2_w2,    dim3(8),      dim3(256), 0, stream, ctx, w_out, W2p);
  hipLaunchKernelGGL(k5_out,     dim3(512),    dim3(256), 0, stream, xn, Wqp, W2p, b_out, gamma2, out);
}